// Round 15
// baseline (447.774 us; speedup 1.0000x reference)
//
#include <hip/hip_runtime.h>
#include <math.h>

// Graph normalizing flow on MI355X.
// State x (N x 128) fp32 lives in d_out; PRESCALED bf16 mirror xb = dinv*x for gathers.
// ldj at d_out[N*128]. Weightless CSR (col only, 4B/edge).
// CSR build atomic-free in global: LDS histograms + rank, reduce, scatter.
// h1 hidden stored fp8 e4m3 prescaled by dinv (halves the big gather's bytes).
// PROPAGATES are FEATURE-SLICED + XCD-AFFINE: slice = blockIdx.x & 1 is constant
// per XCD under the round-robin bid%8 mapping -> per-XCD gather footprint halves
// (6.4 -> 3.2MB, fits the 4MB L2) -> random gathers become L2 hits.
// Dense layers: bf16 MFMA GEMMs (128-thread / 32-row blocks), LDS-staged epilogues.
// ldj: per-block non-atomic partials + deterministic reduce (same-address float
// atomics serialize ~17ns each -> never use them in hot paths).

typedef __attribute__((ext_vector_type(8))) short bf16x8;
typedef __attribute__((ext_vector_type(4))) float f32x4;
typedef __attribute__((ext_vector_type(2))) float f32x2;

#define NCB 64  // CSR count blocks

__device__ __forceinline__ float bf_lo(unsigned int u) { return __uint_as_float(u << 16); }
__device__ __forceinline__ float bf_hi(unsigned int u) { return __uint_as_float(u & 0xffff0000u); }
__device__ __forceinline__ unsigned short f2bf(float f) {
  unsigned int u = __float_as_uint(f);
  u = (u + 0x7fffu + ((u >> 16) & 1u)) >> 16;  // round-to-nearest-even
  return (unsigned short)u;
}
__device__ __forceinline__ unsigned int pack2(float a, float b) {
  return (unsigned int)f2bf(a) | ((unsigned int)f2bf(b) << 16);
}

// ---- fp8 e4m3 (values >= 0 only: h1 is post-relu, prescaled) ----
#if __has_builtin(__builtin_amdgcn_cvt_pk_f32_fp8) && __has_builtin(__builtin_amdgcn_cvt_pk_fp8_f32)
#define FP8_HW 1
#else
#define FP8_HW 0
#endif

__device__ __forceinline__ void fp8x4_dec(unsigned int u, float* o) {
#if FP8_HW
  f32x2 lo = __builtin_amdgcn_cvt_pk_f32_fp8(u, false);
  f32x2 hi = __builtin_amdgcn_cvt_pk_f32_fp8(u, true);
  o[0] = lo[0]; o[1] = lo[1]; o[2] = hi[0]; o[3] = hi[1];
#else
#pragma unroll
  for (int k = 0; k < 4; ++k) {
    unsigned b = (u >> (k * 8)) & 0xff;
    unsigned e = (b >> 3) & 15, mn = b & 7;
    o[k] = e ? __uint_as_float(((e + 120) << 23) | (mn << 20)) : (float)mn * 0.001953125f;
  }
#endif
}

__device__ __forceinline__ unsigned int fp8_enc1(float f) {  // f >= 0
  f = fminf(f, 448.f);
  unsigned u = __float_as_uint(f);
  int e = (int)(u >> 23) - 127;
  if (e < -9) return 0u;
  if (e < -6) return (unsigned)__float2int_rn(f * 512.f);
  unsigned mant = u & 0x7fffffu;
  unsigned r = mant >> 20;
  unsigned rem = mant & 0xfffffu;
  if (rem > 0x80000u || (rem == 0x80000u && (r & 1))) r++;
  unsigned ef = (unsigned)(e + 7);
  if (r == 8) { r = 0; ef++; }
  if (ef > 15) { ef = 15; r = 7; }
  return (ef << 3) | r;
}

__device__ __forceinline__ unsigned int fp8x4_enc(float a, float b, float c, float d) {
#if FP8_HW
  unsigned int u = __builtin_amdgcn_cvt_pk_fp8_f32(a, b, 0u, false);
  u = __builtin_amdgcn_cvt_pk_fp8_f32(c, d, u, true);
  return u;
#else
  return fp8_enc1(a) | (fp8_enc1(b) << 8) | (fp8_enc1(c) << 16) | (fp8_enc1(d) << 24);
#endif
}

// ===== CSR build step 1: per-chunk LDS histogram + local ranks.
__global__ __launch_bounds__(1024) void count_lds_kernel(
    const int* __restrict__ dst, unsigned short* __restrict__ rank,
    unsigned int* __restrict__ blockhist, int e, int nh2, int chunk) {
  extern __shared__ unsigned int hist2[];
  for (int j = threadIdx.x; j < nh2; j += 1024) hist2[j] = 0;
  __syncthreads();
  int b = blockIdx.x;
  int beg = b * chunk;
  int end = min(beg + chunk, e);
  for (int i = beg + threadIdx.x; i < end; i += 1024) {
    int d = dst[i];
    unsigned int old = atomicAdd(&hist2[d >> 1], (d & 1) ? 65536u : 1u);
    rank[i] = (unsigned short)((d & 1) ? (old >> 16) : (old & 0xffffu));
  }
  __syncthreads();
  unsigned int* outp = blockhist + (size_t)b * nh2;
  for (int j = threadIdx.x; j < nh2; j += 1024) outp[j] = hist2[j];
}

// ===== CSR build step 2: column-wise exclusive prefix over blocks, in place.
__global__ void hist_reduce_kernel(unsigned short* __restrict__ bh16,
                                   int* __restrict__ cnt, int n, int stride16) {
  int d = blockIdx.x * blockDim.x + threadIdx.x;
  if (d >= n) return;
  int sum = 0;
#pragma unroll 4
  for (int b = 0; b < NCB; ++b) {
    size_t idx = (size_t)b * stride16 + d;
    int v = bh16[idx];
    bh16[idx] = (unsigned short)sum;
    sum += v;
  }
  cnt[d] = sum;
}

// --- parallel exclusive scan over (cnt[i]+1) [self-loop]; also emits dinv ---
__global__ void scan_blk_kernel(const int* __restrict__ cnt, int* __restrict__ row_ptr,
                                int* __restrict__ bsum, float* __restrict__ dinv, int n) {
  __shared__ int sdata[1024];
  int tid = threadIdx.x;
  int i = blockIdx.x * 1024 + tid;
  int v = (i < n) ? (cnt[i] + 1) : 0;
  if (i < n) dinv[i] = rsqrtf((float)v);
  sdata[tid] = v;
  __syncthreads();
  for (int d = 1; d < 1024; d <<= 1) {
    int t = (tid >= d) ? sdata[tid - d] : 0;
    __syncthreads();
    sdata[tid] += t;
    __syncthreads();
  }
  if (i < n) row_ptr[i] = sdata[tid] - v;
  if (tid == 1023) bsum[blockIdx.x] = sdata[1023];
}

__global__ void scan_top_kernel(int* __restrict__ bsum, int nb) {
  __shared__ int sdata[1024];
  int tid = threadIdx.x;
  int v = (tid < nb) ? bsum[tid] : 0;
  sdata[tid] = v;
  __syncthreads();
  for (int d = 1; d < 1024; d <<= 1) {
    int t = (tid >= d) ? sdata[tid - d] : 0;
    __syncthreads();
    sdata[tid] += t;
    __syncthreads();
  }
  if (tid < nb) bsum[tid] = sdata[tid] - v;
}

// Fused: finalize row_ptr (+ block offsets) AND init out/xb mirror (needs dinv).
__global__ void scan_add_init_kernel(int* __restrict__ row_ptr, const int* __restrict__ bsum,
                                     const float4* __restrict__ x4, float4* __restrict__ out4,
                                     uint2* __restrict__ xb2, const float* __restrict__ dinv,
                                     int n, int m, int total4) {
  int i = blockIdx.x * blockDim.x + threadIdx.x;
  if (i < n) row_ptr[i] += bsum[i >> 10];
  if (i == 0) row_ptr[n] = m;
  if (i < total4) {
    float4 v = x4[i];
    out4[i] = v;
    float dv = dinv[i >> 5];
    xb2[i] = make_uint2(pack2(v.x * dv, v.y * dv), pack2(v.z * dv, v.w * dv));
  }
}

// Atomic-free fill: pos = row_ptr[d] + blockoffset[b][d] + local rank; self-loop last.
__global__ void fill_kernel(const int* __restrict__ src, const int* __restrict__ dst,
                            const unsigned short* __restrict__ rank,
                            const unsigned short* __restrict__ offs16,
                            const int* __restrict__ row_ptr, const int* __restrict__ cnt,
                            int* __restrict__ col, int e, int n, int chunk, int stride16) {
  int i = blockIdx.x * blockDim.x + threadIdx.x;
  if (i < e) {
    int d = dst[i];
    int b = i / chunk;
    int pos = row_ptr[d] + (int)offs16[(size_t)b * stride16 + d] + (int)rank[i];
    col[pos] = src[i];
  } else if (i < e + n) {
    int v = i - e;
    col[row_ptr[v] + cnt[v]] = v;
  }
}

// Build bf16 transposed weight mats + fp32 bias vectors for all 4 half-steps.
__global__ void prep_weights(const float* __restrict__ W, const float* __restrict__ B,
                             unsigned short* __restrict__ WT0, unsigned short* __restrict__ WT1,
                             float* __restrict__ b0c, float* __restrict__ b1c) {
  int idx = blockIdx.x * blockDim.x + threadIdx.x;
  if (idx < 65536) {
    int hsi = idx >> 14;
    int lay = (idx >> 13) & 1;
    int j = (idx >> 6) & 127;
    int k = idx & 63;
    int i = hsi >> 1, half = hsi & 1;
    int g = half * 4 + (j < 64 ? 0 : 2) + i;
    float v = W[(((size_t)g * 2 + lay) * 64 + k) * 64 + (j & 63)];
    unsigned short* dst = lay ? WT1 : WT0;
    dst[(size_t)hsi * 8192 + j * 64 + k] = f2bf(v);
  }
  if (idx < 1024) {
    int hsi = idx >> 8;
    int lay = (idx >> 7) & 1;
    int j = idx & 127;
    int i = hsi >> 1, half = hsi & 1;
    int g = half * 4 + (j < 64 ? 0 : 2) + i;
    (lay ? b1c : b0c)[hsi * 128 + j] = B[(g * 2 + lay) * 64 + (j & 63)];
  }
}

// ===== bf16 propagate, feature-sliced: slice = bid&1 owns 32 of the 64 input feats.
// One wave per node per slice. LPR=4 lanes x uint4 (8 bf16), EPG=16, UNR=2 -> 32
// positions per batch (covers deg<=32 in one pass). Y[d] = dinv[d]*sum (slice cols).
__global__ __launch_bounds__(256, 1) void propagate_bf16_kernel(
    const uint4* __restrict__ X, int xoff4, uint4* __restrict__ Y,
    const int* __restrict__ row_ptr, const int* __restrict__ col,
    const float* __restrict__ dinv, int n) {
  constexpr int EPG = 16, UNR = 2;
  int slice = blockIdx.x & 1;
  int wid0 = (((blockIdx.x >> 1) << 8) + (int)threadIdx.x) >> 6;
  if (wid0 >= n) return;
  int wid = __builtin_amdgcn_readfirstlane(wid0);
  int lane = threadIdx.x & 63;
  int eo = lane >> 2;  // edge slot 0..15
  int li = lane & 3;   // uint4 within the 64B slice
  int soff = xoff4 + slice * 4 + li;  // xb row = 16 uint4
  int beg = row_ptr[wid], end = row_ptr[wid + 1];
  float a0 = 0.f, a1 = 0.f, a2 = 0.f, a3 = 0.f, a4 = 0.f, a5 = 0.f, a6 = 0.f, a7 = 0.f;
  for (int i = beg + eo; i < end; i += UNR * EPG) {
    int cc[UNR];
    uint4 uu[UNR];
    float vv[UNR];
#pragma unroll
    for (int k = 0; k < UNR; ++k) {
      int idx = i + k * EPG;
      cc[k] = col[idx < end ? idx : end - 1];
      vv[k] = (idx < end) ? 1.f : 0.f;
    }
#pragma unroll
    for (int k = 0; k < UNR; ++k) uu[k] = X[(size_t)cc[k] * 16 + soff];
#pragma unroll
    for (int k = 0; k < UNR; ++k) {
      a0 += vv[k] * bf_lo(uu[k].x); a1 += vv[k] * bf_hi(uu[k].x);
      a2 += vv[k] * bf_lo(uu[k].y); a3 += vv[k] * bf_hi(uu[k].y);
      a4 += vv[k] * bf_lo(uu[k].z); a5 += vv[k] * bf_hi(uu[k].z);
      a6 += vv[k] * bf_lo(uu[k].w); a7 += vv[k] * bf_hi(uu[k].w);
    }
  }
#pragma unroll
  for (int ms = 4; ms < 64; ms <<= 1) {
    a0 += __shfl_xor(a0, ms); a1 += __shfl_xor(a1, ms);
    a2 += __shfl_xor(a2, ms); a3 += __shfl_xor(a3, ms);
    a4 += __shfl_xor(a4, ms); a5 += __shfl_xor(a5, ms);
    a6 += __shfl_xor(a6, ms); a7 += __shfl_xor(a7, ms);
  }
  if (lane < 4) {
    float ds = dinv[wid];
    uint4 r;
    r.x = pack2(a0 * ds, a1 * ds);
    r.y = pack2(a2 * ds, a3 * ds);
    r.z = pack2(a4 * ds, a5 * ds);
    r.w = pack2(a6 * ds, a7 * ds);
    Y[(size_t)wid * 8 + slice * 4 + li] = r;  // p row = 8 uint4 (128B)
  }
}

// ===== fp8 propagate, feature-sliced: slice = bid&1 owns 64 of the 128 feats.
// LPR=8 lanes x uint2 (8 fp8), EPG=8, UNR=4 -> 32 positions/batch. q = dinv[d]*sum.
__global__ __launch_bounds__(256, 1) void propagate_fp8_kernel(
    const uint2* __restrict__ X, uint4* __restrict__ Y, const int* __restrict__ row_ptr,
    const int* __restrict__ col, const float* __restrict__ dinv, int n) {
  constexpr int EPG = 8, UNR = 4;
  int slice = blockIdx.x & 1;
  int wid0 = (((blockIdx.x >> 1) << 8) + (int)threadIdx.x) >> 6;
  if (wid0 >= n) return;
  int wid = __builtin_amdgcn_readfirstlane(wid0);
  int lane = threadIdx.x & 63;
  int eo = lane >> 3;  // edge slot 0..7
  int li = lane & 7;   // uint2 within the 64B slice
  int soff = slice * 8 + li;  // h1 row = 16 uint2
  int beg = row_ptr[wid], end = row_ptr[wid + 1];
  float a0 = 0.f, a1 = 0.f, a2 = 0.f, a3 = 0.f, a4 = 0.f, a5 = 0.f, a6 = 0.f, a7 = 0.f;
  for (int i = beg + eo; i < end; i += UNR * EPG) {
    int cc[UNR];
    uint2 uu[UNR];
    float vv[UNR];
#pragma unroll
    for (int k = 0; k < UNR; ++k) {
      int idx = i + k * EPG;
      cc[k] = col[idx < end ? idx : end - 1];
      vv[k] = (idx < end) ? 1.f : 0.f;
    }
#pragma unroll
    for (int k = 0; k < UNR; ++k) uu[k] = X[(size_t)cc[k] * 16 + soff];
#pragma unroll
    for (int k = 0; k < UNR; ++k) {
      float f[8];
      fp8x4_dec(uu[k].x, f);
      fp8x4_dec(uu[k].y, f + 4);
      a0 += vv[k] * f[0]; a1 += vv[k] * f[1];
      a2 += vv[k] * f[2]; a3 += vv[k] * f[3];
      a4 += vv[k] * f[4]; a5 += vv[k] * f[5];
      a6 += vv[k] * f[6]; a7 += vv[k] * f[7];
    }
  }
#pragma unroll
  for (int ms = 8; ms < 64; ms <<= 1) {
    a0 += __shfl_xor(a0, ms); a1 += __shfl_xor(a1, ms);
    a2 += __shfl_xor(a2, ms); a3 += __shfl_xor(a3, ms);
    a4 += __shfl_xor(a4, ms); a5 += __shfl_xor(a5, ms);
    a6 += __shfl_xor(a6, ms); a7 += __shfl_xor(a7, ms);
  }
  if (lane < 8) {
    float ds = dinv[wid];
    uint4 r;
    r.x = pack2(a0 * ds, a1 * ds);
    r.y = pack2(a2 * ds, a3 * ds);
    r.z = pack2(a4 * ds, a5 * ds);
    r.w = pack2(a6 * ds, a7 * ds);
    Y[(size_t)wid * 16 + slice * 8 + li] = r;  // q row = 16 uint4 (256B)
  }
}

// h1[r][j] = fp8(dinv[r] * relu(p[r] @ Wcat0 + b0cat)). 128 threads, 32 rows/block.
__global__ __launch_bounds__(128) void gemm_layer0(const unsigned short* __restrict__ P,
                                                   const unsigned short* __restrict__ WT,
                                                   const float* __restrict__ bc,
                                                   const float* __restrict__ dinv,
                                                   unsigned char* __restrict__ H1, int n) {
  __shared__ unsigned short cs[32][136];
  int w = threadIdx.x >> 6, l = threadIdx.x & 63;
  int rbase0 = blockIdx.x * 32;
  int lr = l & 15, kg = l >> 4;
  int arow = rbase0 + w * 16 + lr;
  if (arow >= n) arow = n - 1;  // clamp; result discarded by guarded store
  const bf16x8* ap = (const bf16x8*)(P + (size_t)arow * 64);
  bf16x8 a0 = ap[kg];
  bf16x8 a1 = ap[kg + 4];
  f32x4 acc[8];
#pragma unroll
  for (int ct = 0; ct < 8; ++ct) {
    const bf16x8* bp = (const bf16x8*)(WT + (size_t)(ct * 16 + lr) * 64);
    f32x4 c = {0.f, 0.f, 0.f, 0.f};
    c = __builtin_amdgcn_mfma_f32_16x16x32_bf16(a0, bp[kg], c, 0, 0, 0);
    c = __builtin_amdgcn_mfma_f32_16x16x32_bf16(a1, bp[kg + 4], c, 0, 0, 0);
    acc[ct] = c;
  }
#pragma unroll
  for (int ct = 0; ct < 8; ++ct) {
    int colj = ct * 16 + lr;
    float bb = bc[colj];
#pragma unroll
    for (int i2 = 0; i2 < 4; ++i2) {
      int lrow = w * 16 + kg * 4 + i2;  // C/D: col=lane&15, row=(lane>>4)*4+reg
      cs[lrow][colj] = f2bf(fmaxf(acc[ct][i2] + bb, 0.f));
    }
  }
  __syncthreads();
  int row = threadIdx.x >> 2;
  int seg = threadIdx.x & 3;  // 32 values each
  if (rbase0 + row < n) {
    float dr = dinv[rbase0 + row];
    const uint4* lp = (const uint4*)&cs[row][seg * 32];
    unsigned int ou[8];
#pragma unroll
    for (int j = 0; j < 4; ++j) {
      uint4 v = lp[j];
      ou[j * 2] = fp8x4_enc(dr * bf_lo(v.x), dr * bf_hi(v.x), dr * bf_lo(v.y), dr * bf_hi(v.y));
      ou[j * 2 + 1] = fp8x4_enc(dr * bf_lo(v.z), dr * bf_hi(v.z), dr * bf_lo(v.w), dr * bf_hi(v.w));
    }
    uint4* dstp = (uint4*)(H1 + (size_t)(rbase0 + row) * 128 + seg * 32);
    dstp[0] = make_uint4(ou[0], ou[1], ou[2], ou[3]);
    dstp[1] = make_uint4(ou[4], ou[5], ou[6], ou[7]);
  }
}

// s=sigmoid(q[:,:64]@Ws1+bs), t=sigmoid(q[:,64:]@Wt1+bt). 128 threads, 32 rows/block.
// Phase2: float4 RMW of Xout half + prescaled bf16-mirror stores; ldj partial.
__global__ __launch_bounds__(128) void gemm_final(const unsigned short* __restrict__ Q,
                                                  const unsigned short* __restrict__ WT,
                                                  const float* __restrict__ bc,
                                                  const float* __restrict__ dinv,
                                                  float* __restrict__ Xout,
                                                  unsigned short* __restrict__ Xb, int xoff,
                                                  float* __restrict__ partials, int n) {
  __shared__ float es[32][68];
  __shared__ float tv[32][68];
  __shared__ float redbuf[2];
  int w = threadIdx.x >> 6, l = threadIdx.x & 63;
  int rbase0 = blockIdx.x * 32;
  int lr = l & 15, kg = l >> 4;
  int arow = rbase0 + w * 16 + lr;
  if (arow >= n) arow = n - 1;
  const bf16x8* ap = (const bf16x8*)(Q + (size_t)arow * 128);
  bf16x8 as0 = ap[kg], as1 = ap[kg + 4];
  bf16x8 at0 = ap[kg + 8], at1 = ap[kg + 12];
  f32x4 acc[8];
#pragma unroll
  for (int ct = 0; ct < 8; ++ct) {
    const bf16x8* bp = (const bf16x8*)(WT + (size_t)(ct * 16 + lr) * 64);
    f32x4 c = {0.f, 0.f, 0.f, 0.f};
    bf16x8 x0 = (ct < 4) ? as0 : at0;
    bf16x8 x1 = (ct < 4) ? as1 : at1;
    c = __builtin_amdgcn_mfma_f32_16x16x32_bf16(x0, bp[kg], c, 0, 0, 0);
    c = __builtin_amdgcn_mfma_f32_16x16x32_bf16(x1, bp[kg + 4], c, 0, 0, 0);
    acc[ct] = c;
  }
  float wldj = 0.f;
#pragma unroll
  for (int ct = 0; ct < 4; ++ct) {
    int colj = ct * 16 + lr;
    float bs = bc[colj], bt = bc[colj + 64];
#pragma unroll
    for (int i2 = 0; i2 < 4; ++i2) {
      int lrow = w * 16 + kg * 4 + i2;
      float sv = 1.f / (1.f + __expf(-(acc[ct][i2] + bs)));
      float tvv = 1.f / (1.f + __expf(-(acc[ct + 4][i2] + bt)));
      es[lrow][colj] = __expf(sv);
      tv[lrow][colj] = tvv;
      if (rbase0 + lrow < n) wldj += sv;
    }
  }
#pragma unroll
  for (int off2 = 32; off2 > 0; off2 >>= 1) wldj += __shfl_down(wldj, off2);
  if (l == 0) redbuf[w] = wldj;
  __syncthreads();
  if (threadIdx.x == 0) partials[blockIdx.x] = redbuf[0] + redbuf[1];
  int row = threadIdx.x >> 2;
  int c0 = (threadIdx.x & 3) * 16;
  int grow = rbase0 + row;
  if (grow < n) {
    float dr = dinv[grow];
    size_t base = (size_t)grow * 128 + xoff;
#pragma unroll
    for (int ci = 0; ci < 4; ++ci) {
      int c = c0 + ci * 4;
      float4 xv = *(const float4*)(Xout + base + c);
      float4 nv;
      nv.x = xv.x * es[row][c + 0] + tv[row][c + 0];
      nv.y = xv.y * es[row][c + 1] + tv[row][c + 1];
      nv.z = xv.z * es[row][c + 2] + tv[row][c + 2];
      nv.w = xv.w * es[row][c + 3] + tv[row][c + 3];
      *(float4*)(Xout + base + c) = nv;
      uint2 bb;
      bb.x = pack2(nv.x * dr, nv.y * dr);
      bb.y = pack2(nv.z * dr, nv.w * dr);
      *(uint2*)(Xb + base + c) = bb;
    }
  }
}

// Deterministic single-block sum of np partials -> *ldj_out (overwrite).
__global__ void ldj_reduce_kernel(const float* __restrict__ partials, int np,
                                  float* __restrict__ ldj_out) {
  __shared__ float sdata[1024];
  int tid = threadIdx.x;
  float a = 0.f;
  for (int i = tid; i < np; i += 1024) a += partials[i];
  sdata[tid] = a;
  __syncthreads();
  for (int d = 512; d > 0; d >>= 1) {
    if (tid < d) sdata[tid] += sdata[tid + d];
    __syncthreads();
  }
  if (tid == 0) *ldj_out = sdata[0];
}

extern "C" void kernel_launch(void* const* d_in, const int* in_sizes, int n_in,
                              void* d_out, int out_size, void* d_ws, size_t ws_size,
                              hipStream_t stream) {
  const float* x = (const float*)d_in[0];
  const int* eidx = (const int*)d_in[1];
  const float* W = (const float*)d_in[2];
  const float* B = (const float*)d_in[3];
  float* out = (float*)d_out;

  int n = in_sizes[0] / 128;
  int e = in_sizes[1] / 2;
  int m = e + n;
  const int* src = eidx;
  const int* dstv = eidx + e;

  size_t off = 0;
  auto alloc = [&](size_t bytes) {
    size_t r = off;
    off += (bytes + 255) & ~(size_t)255;
    return r;
  };
  char* ws = (char*)d_ws;
  int* cnt = (int*)(ws + alloc((size_t)n * 4));
  unsigned short* rank = (unsigned short*)(ws + alloc((size_t)e * 2));
  int* row_ptr = (int*)(ws + alloc((size_t)(n + 1) * 4));
  int* bsum = (int*)(ws + alloc((size_t)1024 * 4));
  float* dinv = (float*)(ws + alloc((size_t)n * 4));
  int* col = (int*)(ws + alloc((size_t)m * 4));
  int nh2 = (n + 1) >> 1;
  int stride16 = nh2 * 2;
  unsigned int* blockhist = (unsigned int*)(ws + alloc((size_t)NCB * nh2 * 4));
  unsigned short* p = (unsigned short*)(ws + alloc((size_t)n * 64 * 2));    // bf16 A~*x_in
  unsigned char* h1 = (unsigned char*)(ws + alloc((size_t)n * 128));        // fp8 hidden
  unsigned short* q = (unsigned short*)(ws + alloc((size_t)n * 128 * 2));   // bf16 A~*h1
  unsigned short* xb = (unsigned short*)(ws + alloc((size_t)n * 128 * 2));  // bf16 prescaled state
  unsigned short* wt0 = (unsigned short*)(ws + alloc((size_t)4 * 8192 * 2));
  unsigned short* wt1 = (unsigned short*)(ws + alloc((size_t)4 * 8192 * 2));
  float* b0c = (float*)(ws + alloc((size_t)4 * 128 * 4));
  float* b1c = (float*)(ws + alloc((size_t)4 * 128 * 4));
  int gblk = (n + 31) / 32;
  float* partials = (float*)(ws + alloc((size_t)4 * gblk * 4));

  int total4 = n * 32;  // float4 elements of state
  int nb = (n + 1023) / 1024;
  int chunk = (e + NCB - 1) / NCB;

  count_lds_kernel<<<NCB, 1024, (size_t)nh2 * 4, stream>>>(dstv, rank, blockhist, e, nh2, chunk);
  hist_reduce_kernel<<<(n + 255) / 256, 256, 0, stream>>>((unsigned short*)blockhist, cnt, n,
                                                          stride16);
  scan_blk_kernel<<<nb, 1024, 0, stream>>>(cnt, row_ptr, bsum, dinv, n);
  scan_top_kernel<<<1, 1024, 0, stream>>>(bsum, nb);
  scan_add_init_kernel<<<(total4 + 255) / 256, 256, 0, stream>>>(
      row_ptr, bsum, (const float4*)x, (float4*)out, (uint2*)xb, dinv, n, m, total4);
  fill_kernel<<<(m + 255) / 256, 256, 0, stream>>>(src, dstv, rank, (unsigned short*)blockhist,
                                                   row_ptr, cnt, col, e, n, chunk, stride16);
  prep_weights<<<256, 256, 0, stream>>>(W, B, wt0, wt1, b0c, b1c);

  const int hs_xin[4] = {0, 64, 0, 64};
  int pgrid2 = 2 * ((n * 64 + 255) / 256);  // 2 feature-slices x one wave per node
  for (int hsi = 0; hsi < 4; ++hsi) {
    int xin = hs_xin[hsi];
    int xout = 64 - xin;
    // p = A~ * x_in (64 feats bf16 prescaled), feature-sliced 2x32
    propagate_bf16_kernel<<<pgrid2, 256, 0, stream>>>(
        (const uint4*)xb, xin / 8, (uint4*)p, row_ptr, col, dinv, n);
    gemm_layer0<<<gblk, 128, 0, stream>>>(p, wt0 + (size_t)hsi * 8192, b0c + hsi * 128, dinv,
                                          h1, n);
    // q = A~ * h1 (128 feats fp8 prescaled), feature-sliced 2x64
    propagate_fp8_kernel<<<pgrid2, 256, 0, stream>>>(
        (const uint2*)h1, (uint4*)q, row_ptr, col, dinv, n);
    gemm_final<<<gblk, 128, 0, stream>>>(q, wt1 + (size_t)hsi * 8192, b1c + hsi * 128, dinv,
                                         out, xb, xout, partials + (size_t)hsi * gblk, n);
  }
  ldj_reduce_kernel<<<1, 1024, 0, stream>>>(partials, 4 * gblk, out + total4 * 4);
}

// Round 16
// 330.053 us; speedup vs baseline: 1.3567x; 1.3567x over previous
//
#include <hip/hip_runtime.h>
#include <math.h>

// Graph normalizing flow on MI355X.
// State x (N x 128) fp32 lives in d_out; PRESCALED bf16 mirror xb = dinv*x for gathers.
// ldj at d_out[N*128]. Weightless CSR (col only, 4B/edge).
// CSR build atomic-free in global: 64 blocks of LDS histograms (packed u16-pair
// atomics) emit per-edge local rank; scan_blk folds the per-block column prefix
// (count->offset in place) + node scan + dinv; fill scatters rank+offset.
// Self-loop slot = row_ptr[v+1]-1 (always last).
// h1 hidden stored fp8 e4m3 prescaled by dinv (halves the big gather's bytes).
// Propagates: one wave/node, 32-position predicated batches (deg<=32 one pass),
// 8 accumulators/lane (r13: wider per-lane loses to the deeper reduce tree;
// r15: feature-slicing loses to cache-line granularity - rows are 1-2 lines).
// Dense layers: bf16 MFMA GEMMs (128-thread / 32-row blocks), LDS-staged epilogues.
// ldj: per-block non-atomic partials + deterministic reduce (same-address float
// atomics serialize ~17ns each -> never use them in hot paths).

typedef __attribute__((ext_vector_type(8))) short bf16x8;
typedef __attribute__((ext_vector_type(4))) float f32x4;
typedef __attribute__((ext_vector_type(2))) float f32x2;

#define NCB 64  // CSR count blocks

__device__ __forceinline__ float bf_lo(unsigned int u) { return __uint_as_float(u << 16); }
__device__ __forceinline__ float bf_hi(unsigned int u) { return __uint_as_float(u & 0xffff0000u); }
__device__ __forceinline__ unsigned short f2bf(float f) {
  unsigned int u = __float_as_uint(f);
  u = (u + 0x7fffu + ((u >> 16) & 1u)) >> 16;  // round-to-nearest-even
  return (unsigned short)u;
}
__device__ __forceinline__ unsigned int pack2(float a, float b) {
  return (unsigned int)f2bf(a) | ((unsigned int)f2bf(b) << 16);
}

// ---- fp8 e4m3 (values >= 0 only: h1 is post-relu, prescaled) ----
#if __has_builtin(__builtin_amdgcn_cvt_pk_f32_fp8) && __has_builtin(__builtin_amdgcn_cvt_pk_fp8_f32)
#define FP8_HW 1
#else
#define FP8_HW 0
#endif

__device__ __forceinline__ void fp8x4_dec(unsigned int u, float* o) {
#if FP8_HW
  f32x2 lo = __builtin_amdgcn_cvt_pk_f32_fp8(u, false);
  f32x2 hi = __builtin_amdgcn_cvt_pk_f32_fp8(u, true);
  o[0] = lo[0]; o[1] = lo[1]; o[2] = hi[0]; o[3] = hi[1];
#else
#pragma unroll
  for (int k = 0; k < 4; ++k) {
    unsigned b = (u >> (k * 8)) & 0xff;
    unsigned e = (b >> 3) & 15, mn = b & 7;
    o[k] = e ? __uint_as_float(((e + 120) << 23) | (mn << 20)) : (float)mn * 0.001953125f;
  }
#endif
}

__device__ __forceinline__ unsigned int fp8_enc1(float f) {  // f >= 0
  f = fminf(f, 448.f);
  unsigned u = __float_as_uint(f);
  int e = (int)(u >> 23) - 127;
  if (e < -9) return 0u;
  if (e < -6) return (unsigned)__float2int_rn(f * 512.f);
  unsigned mant = u & 0x7fffffu;
  unsigned r = mant >> 20;
  unsigned rem = mant & 0xfffffu;
  if (rem > 0x80000u || (rem == 0x80000u && (r & 1))) r++;
  unsigned ef = (unsigned)(e + 7);
  if (r == 8) { r = 0; ef++; }
  if (ef > 15) { ef = 15; r = 7; }
  return (ef << 3) | r;
}

__device__ __forceinline__ unsigned int fp8x4_enc(float a, float b, float c, float d) {
#if FP8_HW
  unsigned int u = __builtin_amdgcn_cvt_pk_fp8_f32(a, b, 0u, false);
  u = __builtin_amdgcn_cvt_pk_fp8_f32(c, d, u, true);
  return u;
#else
  return fp8_enc1(a) | (fp8_enc1(b) << 8) | (fp8_enc1(c) << 16) | (fp8_enc1(d) << 24);
#endif
}

// ===== CSR build step 1: per-chunk LDS histogram + local ranks.
// hist2[j] packs u16 counters for nodes 2j (lo) and 2j+1 (hi). Per-block chunk
// < 64K edges -> no u16 overflow / carry. Rank order within a (block,node) is
// arbitrary - CSR order is irrelevant to a sum.
__global__ __launch_bounds__(1024) void count_lds_kernel(
    const int* __restrict__ dst, unsigned short* __restrict__ rank,
    unsigned int* __restrict__ blockhist, int e, int nh2, int chunk) {
  extern __shared__ unsigned int hist2[];
  for (int j = threadIdx.x; j < nh2; j += 1024) hist2[j] = 0;
  __syncthreads();
  int b = blockIdx.x;
  int beg = b * chunk;
  int end = min(beg + chunk, e);
  for (int i = beg + threadIdx.x; i < end; i += 1024) {
    int d = dst[i];
    unsigned int old = atomicAdd(&hist2[d >> 1], (d & 1) ? 65536u : 1u);
    rank[i] = (unsigned short)((d & 1) ? (old >> 16) : (old & 0xffffu));
  }
  __syncthreads();
  unsigned int* outp = blockhist + (size_t)b * nh2;
  for (int j = threadIdx.x; j < nh2; j += 1024) outp[j] = hist2[j];
}

// ===== CSR build step 2 (fused): per-node column prefix over the 64 block
// histograms (count -> offset IN PLACE), degree -> dinv, and per-1024-block
// exclusive scan of (deg+1) for row_ptr.
__global__ __launch_bounds__(1024) void scan_blk_kernel(
    unsigned short* __restrict__ bh16, int stride16, int* __restrict__ row_ptr,
    int* __restrict__ bsum, float* __restrict__ dinv, int n) {
  __shared__ int sdata[1024];
  int tid = threadIdx.x;
  int i = blockIdx.x * 1024 + tid;
  int v = 0;
  if (i < n) {
    int sum = 0;
#pragma unroll 4
    for (int b = 0; b < NCB; ++b) {
      size_t idx = (size_t)b * stride16 + i;
      int t = bh16[idx];
      bh16[idx] = (unsigned short)sum;
      sum += t;
    }
    v = sum + 1;  // + self-loop
    dinv[i] = rsqrtf((float)v);
  }
  sdata[tid] = v;
  __syncthreads();
  for (int d = 1; d < 1024; d <<= 1) {
    int t = (tid >= d) ? sdata[tid - d] : 0;
    __syncthreads();
    sdata[tid] += t;
    __syncthreads();
  }
  if (i < n) row_ptr[i] = sdata[tid] - v;
  if (tid == 1023) bsum[blockIdx.x] = sdata[1023];
}

__global__ void scan_top_kernel(int* __restrict__ bsum, int nb) {
  __shared__ int sdata[1024];
  int tid = threadIdx.x;
  int v = (tid < nb) ? bsum[tid] : 0;
  sdata[tid] = v;
  __syncthreads();
  for (int d = 1; d < 1024; d <<= 1) {
    int t = (tid >= d) ? sdata[tid - d] : 0;
    __syncthreads();
    sdata[tid] += t;
    __syncthreads();
  }
  if (tid < nb) bsum[tid] = sdata[tid] - v;
}

// Fused: finalize row_ptr (+ block offsets), init out/xb mirror (needs dinv),
// AND build bf16 transposed weights + bias vectors (independent work, guarded).
__global__ void scan_add_init_kernel(int* __restrict__ row_ptr, const int* __restrict__ bsum,
                                     const float4* __restrict__ x4, float4* __restrict__ out4,
                                     uint2* __restrict__ xb2, const float* __restrict__ dinv,
                                     const float* __restrict__ W, const float* __restrict__ B,
                                     unsigned short* __restrict__ WT0,
                                     unsigned short* __restrict__ WT1,
                                     float* __restrict__ b0c, float* __restrict__ b1c,
                                     int n, int m, int total4) {
  int i = blockIdx.x * blockDim.x + threadIdx.x;
  if (i < n) row_ptr[i] += bsum[i >> 10];
  if (i == 0) row_ptr[n] = m;
  if (i < total4) {
    float4 v = x4[i];
    out4[i] = v;
    float dv = dinv[i >> 5];
    xb2[i] = make_uint2(pack2(v.x * dv, v.y * dv), pack2(v.z * dv, v.w * dv));
  }
  if (i < 65536) {
    int hsi = i >> 14;
    int lay = (i >> 13) & 1;
    int j = (i >> 6) & 127;
    int k = i & 63;
    int ii = hsi >> 1, half = hsi & 1;
    int g = half * 4 + (j < 64 ? 0 : 2) + ii;
    float v = W[(((size_t)g * 2 + lay) * 64 + k) * 64 + (j & 63)];
    unsigned short* dst = lay ? WT1 : WT0;
    dst[(size_t)hsi * 8192 + j * 64 + k] = f2bf(v);
  }
  if (i < 1024) {
    int hsi = i >> 8;
    int lay = (i >> 7) & 1;
    int j = i & 127;
    int ii = hsi >> 1, half = hsi & 1;
    int g = half * 4 + (j < 64 ? 0 : 2) + ii;
    (lay ? b1c : b0c)[hsi * 128 + j] = B[(g * 2 + lay) * 64 + (j & 63)];
  }
}

// Atomic-free fill: pos = row_ptr[d] + blockoffset[b][d] + local rank.
// Self-loop is always the LAST slot of its row: row_ptr[v+1]-1.
__global__ void fill_kernel(const int* __restrict__ src, const int* __restrict__ dst,
                            const unsigned short* __restrict__ rank,
                            const unsigned short* __restrict__ offs16,
                            const int* __restrict__ row_ptr,
                            int* __restrict__ col, int e, int n, int chunk, int stride16) {
  int i = blockIdx.x * blockDim.x + threadIdx.x;
  if (i < e) {
    int d = dst[i];
    int b = i / chunk;
    int pos = row_ptr[d] + (int)offs16[(size_t)b * stride16 + d] + (int)rank[i];
    col[pos] = src[i];
  } else if (i < e + n) {
    int v = i - e;
    col[row_ptr[v + 1] - 1] = v;
  }
}

// One wave per node, bf16 prescaled input. LPR lanes/row (uint4: 8 -> 64 feats).
// Y[d] = dinv[d] * sum over col list. Predicated 0/1 mask, clamped duplicate loads.
template <int LPR, int UNR>
__global__ __launch_bounds__(256, 1) void propagate_kernel(
    const uint4* __restrict__ X, int ldu4, int xoff4, uint4* __restrict__ Y, int ldy4,
    const int* __restrict__ row_ptr, const int* __restrict__ col,
    const float* __restrict__ dinv, int n) {
  constexpr int EPG = 64 / LPR;  // edge slots per wave
  int wid0 = (blockIdx.x * blockDim.x + threadIdx.x) >> 6;
  if (wid0 >= n) return;
  int wid = __builtin_amdgcn_readfirstlane(wid0);  // wave-uniform -> scalar loads
  int lane = threadIdx.x & 63;
  int eo = lane / LPR;
  int li = lane % LPR;
  int beg = row_ptr[wid], end = row_ptr[wid + 1];
  float a0 = 0.f, a1 = 0.f, a2 = 0.f, a3 = 0.f, a4 = 0.f, a5 = 0.f, a6 = 0.f, a7 = 0.f;
  for (int i = beg + eo; i < end; i += UNR * EPG) {
    int cc[UNR];
    uint4 uu[UNR];
    float vv[UNR];
#pragma unroll
    for (int k = 0; k < UNR; ++k) {
      int idx = i + k * EPG;
      cc[k] = col[idx < end ? idx : end - 1];
    }
#pragma unroll
    for (int k = 0; k < UNR; ++k) {
      int idx = i + k * EPG;
      vv[k] = (idx < end) ? 1.f : 0.f;
      uu[k] = X[(size_t)cc[k] * ldu4 + xoff4 + li];
    }
#pragma unroll
    for (int k = 0; k < UNR; ++k) {
      a0 += vv[k] * bf_lo(uu[k].x); a1 += vv[k] * bf_hi(uu[k].x);
      a2 += vv[k] * bf_lo(uu[k].y); a3 += vv[k] * bf_hi(uu[k].y);
      a4 += vv[k] * bf_lo(uu[k].z); a5 += vv[k] * bf_hi(uu[k].z);
      a6 += vv[k] * bf_lo(uu[k].w); a7 += vv[k] * bf_hi(uu[k].w);
    }
  }
#pragma unroll
  for (int ms = LPR; ms < 64; ms <<= 1) {
    a0 += __shfl_xor(a0, ms); a1 += __shfl_xor(a1, ms);
    a2 += __shfl_xor(a2, ms); a3 += __shfl_xor(a3, ms);
    a4 += __shfl_xor(a4, ms); a5 += __shfl_xor(a5, ms);
    a6 += __shfl_xor(a6, ms); a7 += __shfl_xor(a7, ms);
  }
  if (lane < LPR) {
    float ds = dinv[wid];
    uint4 r;
    r.x = pack2(a0 * ds, a1 * ds);
    r.y = pack2(a2 * ds, a3 * ds);
    r.z = pack2(a4 * ds, a5 * ds);
    r.w = pack2(a6 * ds, a7 * ds);
    Y[(size_t)wid * ldy4 + li] = r;
  }
}

// fp8 prescaled input: 128 feats/row as 16 uint2 (8B/lane), output bf16 q = dinv[d]*sum.
// LPR=16, EPG=4; UNR=8 -> single 32-position predicated batch covers deg<=32.
template <int UNR>
__global__ __launch_bounds__(256, 1) void propagate_fp8_kernel(
    const uint2* __restrict__ X, uint4* __restrict__ Y, const int* __restrict__ row_ptr,
    const int* __restrict__ col, const float* __restrict__ dinv, int n) {
  constexpr int LPR = 16, EPG = 4;
  int wid0 = (blockIdx.x * blockDim.x + threadIdx.x) >> 6;
  if (wid0 >= n) return;
  int wid = __builtin_amdgcn_readfirstlane(wid0);
  int lane = threadIdx.x & 63;
  int eo = lane / LPR;
  int li = lane % LPR;
  int beg = row_ptr[wid], end = row_ptr[wid + 1];
  float a0 = 0.f, a1 = 0.f, a2 = 0.f, a3 = 0.f, a4 = 0.f, a5 = 0.f, a6 = 0.f, a7 = 0.f;
  for (int i = beg + eo; i < end; i += UNR * EPG) {
    int cc[UNR];
    uint2 uu[UNR];
    float vv[UNR];
#pragma unroll
    for (int k = 0; k < UNR; ++k) {
      int idx = i + k * EPG;
      cc[k] = col[idx < end ? idx : end - 1];
      vv[k] = (idx < end) ? 1.f : 0.f;
    }
#pragma unroll
    for (int k = 0; k < UNR; ++k) uu[k] = X[(size_t)cc[k] * 16 + li];
#pragma unroll
    for (int k = 0; k < UNR; ++k) {
      float f[8];
      fp8x4_dec(uu[k].x, f);
      fp8x4_dec(uu[k].y, f + 4);
      a0 += vv[k] * f[0]; a1 += vv[k] * f[1];
      a2 += vv[k] * f[2]; a3 += vv[k] * f[3];
      a4 += vv[k] * f[4]; a5 += vv[k] * f[5];
      a6 += vv[k] * f[6]; a7 += vv[k] * f[7];
    }
  }
#pragma unroll
  for (int ms = LPR; ms < 64; ms <<= 1) {
    a0 += __shfl_xor(a0, ms); a1 += __shfl_xor(a1, ms);
    a2 += __shfl_xor(a2, ms); a3 += __shfl_xor(a3, ms);
    a4 += __shfl_xor(a4, ms); a5 += __shfl_xor(a5, ms);
    a6 += __shfl_xor(a6, ms); a7 += __shfl_xor(a7, ms);
  }
  if (lane < LPR) {
    float ds = dinv[wid];
    uint4 r;
    r.x = pack2(a0 * ds, a1 * ds);
    r.y = pack2(a2 * ds, a3 * ds);
    r.z = pack2(a4 * ds, a5 * ds);
    r.w = pack2(a6 * ds, a7 * ds);
    Y[(size_t)wid * 16 + li] = r;
  }
}

// h1[r][j] = fp8(dinv[r] * relu(p[r] @ Wcat0 + b0cat)). 128 threads, 32 rows/block.
__global__ __launch_bounds__(128) void gemm_layer0(const unsigned short* __restrict__ P,
                                                   const unsigned short* __restrict__ WT,
                                                   const float* __restrict__ bc,
                                                   const float* __restrict__ dinv,
                                                   unsigned char* __restrict__ H1, int n) {
  __shared__ unsigned short cs[32][136];
  int w = threadIdx.x >> 6, l = threadIdx.x & 63;
  int rbase0 = blockIdx.x * 32;
  int lr = l & 15, kg = l >> 4;
  int arow = rbase0 + w * 16 + lr;
  if (arow >= n) arow = n - 1;  // clamp; result discarded by guarded store
  const bf16x8* ap = (const bf16x8*)(P + (size_t)arow * 64);
  bf16x8 a0 = ap[kg];
  bf16x8 a1 = ap[kg + 4];
  f32x4 acc[8];
#pragma unroll
  for (int ct = 0; ct < 8; ++ct) {
    const bf16x8* bp = (const bf16x8*)(WT + (size_t)(ct * 16 + lr) * 64);
    f32x4 c = {0.f, 0.f, 0.f, 0.f};
    c = __builtin_amdgcn_mfma_f32_16x16x32_bf16(a0, bp[kg], c, 0, 0, 0);
    c = __builtin_amdgcn_mfma_f32_16x16x32_bf16(a1, bp[kg + 4], c, 0, 0, 0);
    acc[ct] = c;
  }
#pragma unroll
  for (int ct = 0; ct < 8; ++ct) {
    int colj = ct * 16 + lr;
    float bb = bc[colj];
#pragma unroll
    for (int i2 = 0; i2 < 4; ++i2) {
      int lrow = w * 16 + kg * 4 + i2;  // C/D: col=lane&15, row=(lane>>4)*4+reg
      cs[lrow][colj] = f2bf(fmaxf(acc[ct][i2] + bb, 0.f));
    }
  }
  __syncthreads();
  int row = threadIdx.x >> 2;
  int seg = threadIdx.x & 3;  // 32 values each
  if (rbase0 + row < n) {
    float dr = dinv[rbase0 + row];
    const uint4* lp = (const uint4*)&cs[row][seg * 32];
    unsigned int ou[8];
#pragma unroll
    for (int j = 0; j < 4; ++j) {
      uint4 v = lp[j];
      ou[j * 2] = fp8x4_enc(dr * bf_lo(v.x), dr * bf_hi(v.x), dr * bf_lo(v.y), dr * bf_hi(v.y));
      ou[j * 2 + 1] = fp8x4_enc(dr * bf_lo(v.z), dr * bf_hi(v.z), dr * bf_lo(v.w), dr * bf_hi(v.w));
    }
    uint4* dstp = (uint4*)(H1 + (size_t)(rbase0 + row) * 128 + seg * 32);
    dstp[0] = make_uint4(ou[0], ou[1], ou[2], ou[3]);
    dstp[1] = make_uint4(ou[4], ou[5], ou[6], ou[7]);
  }
}

// s=sigmoid(q[:,:64]@Ws1+bs), t=sigmoid(q[:,64:]@Wt1+bt). 128 threads, 32 rows/block.
// Phase2: float4 RMW of Xout half + prescaled bf16-mirror stores; ldj partial.
__global__ __launch_bounds__(128) void gemm_final(const unsigned short* __restrict__ Q,
                                                  const unsigned short* __restrict__ WT,
                                                  const float* __restrict__ bc,
                                                  const float* __restrict__ dinv,
                                                  float* __restrict__ Xout,
                                                  unsigned short* __restrict__ Xb, int xoff,
                                                  float* __restrict__ partials, int n) {
  __shared__ float es[32][68];
  __shared__ float tv[32][68];
  __shared__ float redbuf[2];
  int w = threadIdx.x >> 6, l = threadIdx.x & 63;
  int rbase0 = blockIdx.x * 32;
  int lr = l & 15, kg = l >> 4;
  int arow = rbase0 + w * 16 + lr;
  if (arow >= n) arow = n - 1;
  const bf16x8* ap = (const bf16x8*)(Q + (size_t)arow * 128);
  bf16x8 as0 = ap[kg], as1 = ap[kg + 4];
  bf16x8 at0 = ap[kg + 8], at1 = ap[kg + 12];
  f32x4 acc[8];
#pragma unroll
  for (int ct = 0; ct < 8; ++ct) {
    const bf16x8* bp = (const bf16x8*)(WT + (size_t)(ct * 16 + lr) * 64);
    f32x4 c = {0.f, 0.f, 0.f, 0.f};
    bf16x8 x0 = (ct < 4) ? as0 : at0;
    bf16x8 x1 = (ct < 4) ? as1 : at1;
    c = __builtin_amdgcn_mfma_f32_16x16x32_bf16(x0, bp[kg], c, 0, 0, 0);
    c = __builtin_amdgcn_mfma_f32_16x16x32_bf16(x1, bp[kg + 4], c, 0, 0, 0);
    acc[ct] = c;
  }
  float wldj = 0.f;
#pragma unroll
  for (int ct = 0; ct < 4; ++ct) {
    int colj = ct * 16 + lr;
    float bs = bc[colj], bt = bc[colj + 64];
#pragma unroll
    for (int i2 = 0; i2 < 4; ++i2) {
      int lrow = w * 16 + kg * 4 + i2;
      float sv = 1.f / (1.f + __expf(-(acc[ct][i2] + bs)));
      float tvv = 1.f / (1.f + __expf(-(acc[ct + 4][i2] + bt)));
      es[lrow][colj] = __expf(sv);
      tv[lrow][colj] = tvv;
      if (rbase0 + lrow < n) wldj += sv;
    }
  }
#pragma unroll
  for (int off2 = 32; off2 > 0; off2 >>= 1) wldj += __shfl_down(wldj, off2);
  if (l == 0) redbuf[w] = wldj;
  __syncthreads();
  if (threadIdx.x == 0) partials[blockIdx.x] = redbuf[0] + redbuf[1];
  int row = threadIdx.x >> 2;
  int c0 = (threadIdx.x & 3) * 16;
  int grow = rbase0 + row;
  if (grow < n) {
    float dr = dinv[grow];
    size_t base = (size_t)grow * 128 + xoff;
#pragma unroll
    for (int ci = 0; ci < 4; ++ci) {
      int c = c0 + ci * 4;
      float4 xv = *(const float4*)(Xout + base + c);
      float4 nv;
      nv.x = xv.x * es[row][c + 0] + tv[row][c + 0];
      nv.y = xv.y * es[row][c + 1] + tv[row][c + 1];
      nv.z = xv.z * es[row][c + 2] + tv[row][c + 2];
      nv.w = xv.w * es[row][c + 3] + tv[row][c + 3];
      *(float4*)(Xout + base + c) = nv;
      uint2 bb;
      bb.x = pack2(nv.x * dr, nv.y * dr);
      bb.y = pack2(nv.z * dr, nv.w * dr);
      *(uint2*)(Xb + base + c) = bb;
    }
  }
}

// Deterministic single-block sum of np partials -> *ldj_out (overwrite).
__global__ void ldj_reduce_kernel(const float* __restrict__ partials, int np,
                                  float* __restrict__ ldj_out) {
  __shared__ float sdata[1024];
  int tid = threadIdx.x;
  float a = 0.f;
  for (int i = tid; i < np; i += 1024) a += partials[i];
  sdata[tid] = a;
  __syncthreads();
  for (int d = 512; d > 0; d >>= 1) {
    if (tid < d) sdata[tid] += sdata[tid + d];
    __syncthreads();
  }
  if (tid == 0) *ldj_out = sdata[0];
}

extern "C" void kernel_launch(void* const* d_in, const int* in_sizes, int n_in,
                              void* d_out, int out_size, void* d_ws, size_t ws_size,
                              hipStream_t stream) {
  const float* x = (const float*)d_in[0];
  const int* eidx = (const int*)d_in[1];
  const float* W = (const float*)d_in[2];
  const float* B = (const float*)d_in[3];
  float* out = (float*)d_out;

  int n = in_sizes[0] / 128;
  int e = in_sizes[1] / 2;
  int m = e + n;
  const int* src = eidx;
  const int* dstv = eidx + e;

  size_t off = 0;
  auto alloc = [&](size_t bytes) {
    size_t r = off;
    off += (bytes + 255) & ~(size_t)255;
    return r;
  };
  char* ws = (char*)d_ws;
  unsigned short* rank = (unsigned short*)(ws + alloc((size_t)e * 2));
  int* row_ptr = (int*)(ws + alloc((size_t)(n + 1) * 4));
  int* bsum = (int*)(ws + alloc((size_t)1024 * 4));
  float* dinv = (float*)(ws + alloc((size_t)n * 4));
  int* col = (int*)(ws + alloc((size_t)m * 4));
  int nh2 = (n + 1) >> 1;
  int stride16 = nh2 * 2;
  unsigned int* blockhist = (unsigned int*)(ws + alloc((size_t)NCB * nh2 * 4));
  unsigned short* p = (unsigned short*)(ws + alloc((size_t)n * 64 * 2));    // bf16 A~*x_in
  unsigned char* h1 = (unsigned char*)(ws + alloc((size_t)n * 128));        // fp8 hidden
  unsigned short* q = (unsigned short*)(ws + alloc((size_t)n * 128 * 2));   // bf16 A~*h1
  unsigned short* xb = (unsigned short*)(ws + alloc((size_t)n * 128 * 2));  // bf16 prescaled state
  unsigned short* wt0 = (unsigned short*)(ws + alloc((size_t)4 * 8192 * 2));
  unsigned short* wt1 = (unsigned short*)(ws + alloc((size_t)4 * 8192 * 2));
  float* b0c = (float*)(ws + alloc((size_t)4 * 128 * 4));
  float* b1c = (float*)(ws + alloc((size_t)4 * 128 * 4));
  int gblk = (n + 31) / 32;
  float* partials = (float*)(ws + alloc((size_t)4 * gblk * 4));

  int total4 = n * 32;  // float4 elements of state
  int nb = (n + 1023) / 1024;
  int chunk = (e + NCB - 1) / NCB;

  count_lds_kernel<<<NCB, 1024, (size_t)nh2 * 4, stream>>>(dstv, rank, blockhist, e, nh2, chunk);
  scan_blk_kernel<<<nb, 1024, 0, stream>>>((unsigned short*)blockhist, stride16, row_ptr, bsum,
                                           dinv, n);
  scan_top_kernel<<<1, 1024, 0, stream>>>(bsum, nb);
  scan_add_init_kernel<<<(total4 + 255) / 256, 256, 0, stream>>>(
      row_ptr, bsum, (const float4*)x, (float4*)out, (uint2*)xb, dinv, W, B, wt0, wt1, b0c, b1c,
      n, m, total4);
  fill_kernel<<<(m + 255) / 256, 256, 0, stream>>>(src, dstv, rank, (unsigned short*)blockhist,
                                                   row_ptr, col, e, n, chunk, stride16);

  const int hs_xin[4] = {0, 64, 0, 64};
  int pgrid = (n * 64 + 255) / 256;  // one wave per node
  for (int hsi = 0; hsi < 4; ++hsi) {
    int xin = hs_xin[hsi];
    int xout = 64 - xin;
    // p = A~ * x_in (64 feats bf16 prescaled): 8 lanes/row, 8 slots x 4 unroll
    propagate_kernel<8, 4><<<pgrid, 256, 0, stream>>>(
        (const uint4*)xb, 16, xin / 8, (uint4*)p, 8, row_ptr, col, dinv, n);
    gemm_layer0<<<gblk, 128, 0, stream>>>(p, wt0 + (size_t)hsi * 8192, b0c + hsi * 128, dinv,
                                          h1, n);
    // q = A~ * h1 (128 feats fp8 prescaled): 16 lanes/row uint2, 4 slots x 8 unroll
    propagate_fp8_kernel<8><<<pgrid, 256, 0, stream>>>(
        (const uint2*)h1, (uint4*)q, row_ptr, col, dinv, n);
    gemm_final<<<gblk, 128, 0, stream>>>(q, wt1 + (size_t)hsi * 8192, b1c + hsi * 128, dinv,
                                         out, xb, xout, partials + (size_t)hsi * gblk, n);
  }
  ldj_reduce_kernel<<<1, 1024, 0, stream>>>(partials, 4 * gblk, out + total4 * 4);
}